// Round 24
// baseline (49.813 us; speedup 1.0000x reference)
//
#include <hip/hip_runtime.h>
#include <hip/hip_bf16.h>
#include <stdint.h>

#define NROWS 8192
#define BROWS 4096
#define LN2 0.6931471805599453f
#define FSC 8.944507e-4f        // (1/T)*log2(e) / 127^2, T=0.1
#define KMAD 7503               // round(FSC * 2^23)
#define CBITS 1064989150        // (127 - 0.0434) * 2^23  (Schraudolph exp2)
#define NBLK 2112               // sum_{it=0}^{127} ceil((128-it)/4) = 8*264

typedef __attribute__((ext_vector_type(4))) int i32x4;

// C(it) = number of blocks before strip it (exact): 2112 - S(132-it),
// S(n) = sum_{k<n} (k>>2) = 2m(m-1) + r*m with m=n>>2, r=n&3.
__device__ inline int cum_blocks(int it) {
  int n = 132 - it, m = n >> 2, r = n & 3;
  return NBLK - (2 * m * (m - 1) + r * m);
}

// Kernel A: L2-normalize rows, quantize to i8; store qss=sum(q^2); zero denom/out.
__global__ __launch_bounds__(256) void knorm(const float* __restrict__ zi,
                                             const float* __restrict__ zj,
                                             int* __restrict__ reps,   // i8 packed
                                             int* __restrict__ qss,
                                             float* __restrict__ denom,
                                             float* __restrict__ out) {
  int w = threadIdx.x >> 6, l = threadIdx.x & 63;
  int row = blockIdx.x * 4 + w;
  const float* src = (row < BROWS) ? (zi + (size_t)row * 256)
                                   : (zj + (size_t)(row - BROWS) * 256);
  float4 v = ((const float4*)src)[l];
  float ss = v.x * v.x + v.y * v.y + v.z * v.z + v.w * v.w;
#pragma unroll
  for (int m = 1; m < 64; m <<= 1) ss += __shfl_xor(ss, m, 64);
  float sc = 127.0f / fmaxf(sqrtf(ss), 1e-12f);
  int q0 = __float2int_rn(v.x * sc), q1 = __float2int_rn(v.y * sc);
  int q2 = __float2int_rn(v.z * sc), q3 = __float2int_rn(v.w * sc);
  reps[(size_t)row * 64 + l] =
      (q0 & 255) | ((q1 & 255) << 8) | ((q2 & 255) << 16) | ((q3 & 255) << 24);
  int qs = q0 * q0 + q1 * q1 + q2 * q2 + q3 * q3;
#pragma unroll
  for (int m = 1; m < 64; m <<= 1) qs += __shfl_xor(qs, m, 64);
  if (l == 0) { denom[row] = 0.f; qss[row] = qs; }
  if (row == 0 && l == 0) out[0] = 0.f;
}

// Kernel B: barrier-free upper-tri sim, i8 MFMA 16x16x64, ONE WAVE PER BLOCK,
// FULLY REGISTER-RESIDENT B PIPELINE: no LDS staging at all. B-frags for the
// 32-col tile live in 8 VGPR quads, double-buffered (bfA/bfB). Each phase
// issues next tile's 8 loads BEFORE waiting vmcnt(8) for the current tile's
// (issued one full phase earlier -> latency covered). reps is L2-resident.
// Schraudolph exp2 epilogue; diagonal subtracted bit-identically in kfin.
// Block = 64-row strip x 256-col chunk (2112 blocks, XCD-bijective swizzle).
__global__ __launch_bounds__(64, 2) void ksim(const int* __restrict__ reps_,
                                              float* __restrict__ denom,
                                              float* __restrict__ pos) {
  __shared__ float colacc[256];      // 1 KB (single wave: plain adds)
  int l = threadIdx.x;               // 0..63
  int kgrp = l >> 4;

  // ---- closed-form block -> (strip it, chunk q); ALU only ----
  int b = blockIdx.x;
  int orig = (b & 7) * 264 + (b >> 3);     // XCD-bijective swizzle
  float f = 8.0f * (float)(NBLK - orig) + 0.25f;
  int it = 132 - (int)(sqrtf(f) + 0.5f);
  if (it < 0) it = 0;
  if (it > 127) it = 127;
  while (it < 127 && cum_blocks(it + 1) <= orig) ++it;
  while (it > 0 && cum_blocks(it) > orig) --it;
  int q = orig - cum_blocks(it);
  int rowbase = it * 64;
  int cs0 = rowbase + q * 256;
  int len = NROWS - cs0; if (len > 256) len = 256;
  int ntile = len >> 5;              // 2,4,6,8 (always even)

#pragma unroll
  for (int i = 0; i < 4; ++i) colacc[l + 64 * i] = 0.f;

  const uint4* r4 = (const uint4*)reps_;

  // ---- A fragments: 64-row strip; lane holds row rowbase+fr*16+(l&15) ----
  i32x4 a[4][4];
  {
    int arow = rowbase + (l & 15);
#pragma unroll
    for (int fr = 0; fr < 4; ++fr)
#pragma unroll
      for (int kk = 0; kk < 4; ++kk)
        a[fr][kk] = __builtin_bit_cast(i32x4,
            r4[(size_t)(arow + fr * 16) * 16 + kk * 4 + kgrp]);
  }

  // ---- B loads: 8 dwordx4 per 32-col tile; dst[kk]=rows cb+(l&15),
  //      dst[4+kk]=rows cb+16+(l&15), 16B chunk kgrp ----
  auto loadB = [&](i32x4 (&dst)[8], int cb) {
    const uint4* bp = r4 + (size_t)(cb + (l & 15)) * 16 + kgrp;
#pragma unroll
    for (int kk = 0; kk < 4; ++kk) {
      dst[kk]     = __builtin_bit_cast(i32x4, bp[kk * 4]);
      dst[kk + 4] = __builtin_bit_cast(i32x4, bp[kk * 4 + 256]);  // +16 rows
    }
  };

  i32x4 bfA[8], bfB[8];
  loadB(bfA, cs0);                   // tile 0 (A loads + these = 24 in flight)

  float rowsum[4][4];
#pragma unroll
  for (int fr = 0; fr < 4; ++fr)
#pragma unroll
    for (int r = 0; r < 4; ++r) rowsum[fr][r] = 0.f;

  int r0 = rowbase + kgrp * 4;
  const int kmad = KMAD;             // SGPR
  const int cbits = CBITS;           // VGPR (2nd const; 1-SGPR rule)

  // ---- one pipeline step: compute tile t from cur; next tile's loads are
  //      already issued by the caller before the wait ----
  auto step = [&](i32x4 (&cur)[8], int t, bool lastWait) {
    if (lastWait) asm volatile("s_waitcnt vmcnt(0)" ::: "memory");
    else          asm volatile("s_waitcnt vmcnt(8)" ::: "memory");
    __builtin_amdgcn_sched_barrier(0);

    i32x4 acc[4][2];
    const i32x4 zero = {0, 0, 0, 0};
    __builtin_amdgcn_s_setprio(1);
#pragma unroll
    for (int kk = 0; kk < 4; ++kk)
#pragma unroll
      for (int fr = 0; fr < 4; ++fr) {
        if (kk == 0) {
          acc[fr][0] = __builtin_amdgcn_mfma_i32_16x16x64_i8(a[fr][0], cur[0], zero, 0, 0, 0);
          acc[fr][1] = __builtin_amdgcn_mfma_i32_16x16x64_i8(a[fr][0], cur[4], zero, 0, 0, 0);
        } else {
          acc[fr][0] = __builtin_amdgcn_mfma_i32_16x16x64_i8(a[fr][kk], cur[kk], acc[fr][0], 0, 0, 0);
          acc[fr][1] = __builtin_amdgcn_mfma_i32_16x16x64_i8(a[fr][kk], cur[kk + 4], acc[fr][1], 0, 0, 0);
        }
      }
    __builtin_amdgcn_s_setprio(0);

    // ---- epilogue: e = bitcast(mad_i24(I, K, C)); rowsum + colacc (LDS) ----
    int cb = cs0 + 32 * t;
    bool docol = !(q == 0 && t < 2);        // diag 64-col window: rowsum only
    bool dopos = (q == 16) && (t < 2);
    float cp0 = 0.f, cp1 = 0.f;
#pragma unroll
    for (int fr = 0; fr < 4; ++fr)
#pragma unroll
      for (int fc = 0; fc < 2; ++fc)
#pragma unroll
        for (int r = 0; r < 4; ++r) {
          int I = acc[fr][fc][r];
          int ib;
          asm("v_mad_i32_i24 %0, %1, %2, %3"
              : "=v"(ib) : "v"(I), "s"(kmad), "v"(cbits));
          float e = __builtin_bit_cast(float, ib);
          if (dopos) {
            int rg = r0 + fr * 16 + r;
            int cg = cb + (l & 15) + fc * 16;
            if (cg == rg + BROWS) pos[rg] = (float)I * FSC;
          }
          rowsum[fr][r] += e;
          if (fc == 0) cp0 += e; else cp1 += e;
        }
    if (docol) {
      cp0 += __shfl_xor(cp0, 16, 64); cp0 += __shfl_xor(cp0, 32, 64);
      cp1 += __shfl_xor(cp1, 16, 64); cp1 += __shfl_xor(cp1, 32, 64);
      if (l < 16) {
        int off = (cb - cs0) + l;
        colacc[off] += cp0;
        colacc[off + 16] += cp1;
      }
    }
  };

  for (int t = 0; t < ntile; t += 2) {     // ntile always even
    // even tile t (cur=bfA): issue loads for t+1 into bfB, then wait+compute
    if (t + 1 < ntile) loadB(bfB, cs0 + 32 * (t + 1));
    step(bfA, t, /*lastWait=*/t + 1 >= ntile);
    // odd tile t+1 (cur=bfB): issue loads for t+2 into bfA (WAR after MFMAs)
    if (t + 2 < ntile) loadB(bfA, cs0 + 32 * (t + 2));
    step(bfB, t + 1, /*lastWait=*/t + 2 >= ntile);
  }

  // ---- row sums: reduce 16 col-lanes; 4 lanes issue global atomics ----
#pragma unroll
  for (int fr = 0; fr < 4; ++fr)
#pragma unroll
    for (int r = 0; r < 4; ++r) {
      float vv = rowsum[fr][r];
      vv += __shfl_xor(vv, 1, 64);
      vv += __shfl_xor(vv, 2, 64);
      vv += __shfl_xor(vv, 4, 64);
      vv += __shfl_xor(vv, 8, 64);
      if ((l & 15) == 0) atomicAdd(&denom[r0 + fr * 16 + r], vv);
    }

  // ---- col sums: flush colacc, one atomic per nonzero column ----
#pragma unroll
  for (int i = 0; i < 4; ++i) {
    int off = l + 64 * i;
    float vv = colacc[off];
    if (vv != 0.f) atomicAdd(&denom[cs0 + off], vv);
  }
}

// Kernel F: subtract the (bit-identical) diagonal term, then
// + (1/N) * sum_i (log(denom_i) - pos_{i mod B} * ln2)
__global__ __launch_bounds__(256) void kfin(const float* __restrict__ denom,
                                            const float* __restrict__ pos,
                                            const int* __restrict__ qss,
                                            float* __restrict__ out) {
  int i = blockIdx.x * 256 + threadIdx.x;
  int ib = qss[i] * KMAD + CBITS;           // same int formula as ksim's mad_i24
  float diag_e = __builtin_bit_cast(float, ib);
  float v = (logf(denom[i] - diag_e) - pos[i & 4095] * LN2) * (1.0f / 8192.0f);
#pragma unroll
  for (int m = 1; m < 64; m <<= 1) v += __shfl_xor(v, m, 64);
  __shared__ float part[4];
  if ((threadIdx.x & 63) == 0) part[threadIdx.x >> 6] = v;
  __syncthreads();
  if (threadIdx.x == 0)
    atomicAdd(out, part[0] + part[1] + part[2] + part[3]);
}

extern "C" void kernel_launch(void* const* d_in, const int* in_sizes, int n_in,
                              void* d_out, int out_size, void* d_ws, size_t ws_size,
                              hipStream_t stream) {
  (void)in_sizes; (void)n_in; (void)out_size; (void)ws_size;
  const float* zi = (const float*)d_in[0];
  const float* zj = (const float*)d_in[1];
  float* out = (float*)d_out;
  char* ws = (char*)d_ws;
  int* reps    = (int*)ws;                                    // 2 MB (i8 packed)
  float* denom = (float*)(ws + 2097152);                      // 32 KB
  float* pos   = (float*)(ws + 2097152 + 32768);              // 16 KB
  int* qss     = (int*)(ws + 2097152 + 32768 + 16384);        // 32 KB

  knorm<<<2048, 256, 0, stream>>>(zi, zj, reps, qss, denom, out);
  ksim<<<NBLK, 64, 0, stream>>>(reps, denom, pos);
  kfin<<<32, 256, 0, stream>>>(denom, pos, qss, out);
}